// Round 1
// baseline (496.781 us; speedup 1.0000x reference)
//
#include <hip/hip_runtime.h>
#include <hip/hip_bf16.h>
#include <cstdint>

typedef _Float16 half2v __attribute__((ext_vector_type(2)));

// ---------------------------------------------------------------------------
// Kernel 1: RWB[r][n] = dot(rel_features[r,:], W[n,:]) + b[n]   (fp16, [R][128])
// Row-major: gather reads row r as 256 contiguous bytes (L2-resident table).
// ---------------------------------------------------------------------------
__global__ void rwb_row_kernel(const float* __restrict__ rel, const float* __restrict__ W,
                               const float* __restrict__ b, _Float16* __restrict__ rwb,
                               int R) {
    const int k = blockIdx.x;        // relation index
    const int n = threadIdx.x;       // output feature (0..127)
    __shared__ float relk[128];
    relk[n] = rel[(size_t)k * 128 + n];
    __syncthreads();
    const float4* w4 = reinterpret_cast<const float4*>(W + (size_t)n * 128);
    const float4* r4 = reinterpret_cast<const float4*>(relk);
    float acc = 0.f;
#pragma unroll
    for (int i = 0; i < 32; ++i) {
        float4 a = r4[i], w = w4[i];
        acc += a.x * w.x + a.y * w.y + a.z * w.z + a.w * w.w;
    }
    rwb[(size_t)k * 128 + n] = (_Float16)(acc + b[n]);
}

// ---------------------------------------------------------------------------
// Spill path for slot-capacity overflow (statistically unreachable: degrees are
// Poisson(250), CAP >= 384 is >8 sigma). Correctness guard only.
// ---------------------------------------------------------------------------
__device__ __noinline__ void spill_add(float* __restrict__ out, const _Float16* __restrict__ rwb,
                                       int v, int r, float val) {
    float* o = out + (size_t)v * 128;
    const _Float16* rw = rwb + (size_t)r * 128;
    for (int n = 0; n < 128; ++n) unsafeAtomicAdd(o + n, val * (float)rw[n]);
}

// ---------------------------------------------------------------------------
// Kernel 2: build per-entity incidence lists.
// cnt[v*32] is one counter per 128B line (kills same-line serialization);
// slot payload is a plain 8B store {rel, val} -> consecutive positions of the
// same entity share cache lines (16 entries / 128B line), no RMW atomic on the
// 65MB region at all.
// ---------------------------------------------------------------------------
__global__ void scatter2_kernel(const int* __restrict__ heads, const int* __restrict__ tails,
                                const int* __restrict__ rels, const float* __restrict__ val,
                                int* __restrict__ cnt, uint2* __restrict__ slots,
                                const _Float16* __restrict__ rwb, float* __restrict__ out,
                                int E, int CAP) {
    const int i = blockIdx.x * blockDim.x + threadIdx.x;
    if (i >= E) return;
    const int r = rels[i];
    const float v = val[i];
    uint2 pk;
    pk.x = (unsigned)r;
    pk.y = __float_as_uint(v);
    const int t = tails[i];
    const int h = heads[i];
    const int pt = atomicAdd(&cnt[t * 32], 1);
    if (pt < CAP) slots[(size_t)t * CAP + pt] = pk;
    else          spill_add(out, rwb, t, r, v);
    const int ph = atomicAdd(&cnt[h * 32], 1);
    if (ph < CAP) slots[(size_t)h * CAP + ph] = pk;
    else          spill_add(out, rwb, h, r, v);
}

// ---------------------------------------------------------------------------
// Kernel 3: out[v] = relu( out[v] + sum_j val_j * RWB[rel_j] )
// One wave per entity. 2 features/lane (ushort2 = 4B/lane coalesced row load
// from the 512KB L2-hot RWB table). fp32 register accumulation -> better
// precision than the old fp16-atomic S + fp16 GEMM. out holds only the (never
// triggered) spill contributions, pre-zeroed.
// ---------------------------------------------------------------------------
__global__ __launch_bounds__(256) void gather_kernel(
    const uint2* __restrict__ slots, const int* __restrict__ cnt,
    const _Float16* __restrict__ rwb, float* __restrict__ out,
    int NUMENT, int CAP) {
    const int wave = blockIdx.x * (blockDim.x >> 6) + (threadIdx.x >> 6);
    if (wave >= NUMENT) return;
    const int lane = threadIdx.x & 63;
    const int v = wave;
    int deg = cnt[v * 32];
    if (deg > CAP) deg = CAP;
    const uint2* sl = slots + (size_t)v * CAP;
    const unsigned* rwb32 = reinterpret_cast<const unsigned*>(rwb);

    float acc0 = 0.f, acc1 = 0.f;
    int j = 0;
    for (; j + 8 <= deg; j += 8) {
        uint2 e[8];
#pragma unroll
        for (int u = 0; u < 8; ++u) e[u] = sl[j + u];   // wave-uniform 8B loads, 8 in flight
#pragma unroll
        for (int u = 0; u < 8; ++u) {
            const int rel = (int)e[u].x;
            const float w = __uint_as_float(e[u].y);
            const unsigned rw = rwb32[(size_t)rel * 64 + lane];   // 4B/lane, 256B/wave row
            const half2v h = __builtin_bit_cast(half2v, rw);
            acc0 += w * (float)h[0];
            acc1 += w * (float)h[1];
        }
    }
    for (; j < deg; ++j) {
        const uint2 e = sl[j];
        const int rel = (int)e.x;
        const float w = __uint_as_float(e.y);
        const unsigned rw = rwb32[(size_t)rel * 64 + lane];
        const half2v h = __builtin_bit_cast(half2v, rw);
        acc0 += w * (float)h[0];
        acc1 += w * (float)h[1];
    }

    float* op = out + (size_t)v * 128 + lane * 2;
    float2 sp = *reinterpret_cast<const float2*>(op);   // spill contributions (normally 0)
    float2 o;
    o.x = fmaxf(acc0 + sp.x, 0.f);
    o.y = fmaxf(acc1 + sp.y, 0.f);
    *reinterpret_cast<float2*>(op) = o;
}

// ---------------------------------------------------------------------------
// Fallback path (ws too small): direct vector scatter into out.
// ---------------------------------------------------------------------------
__global__ void rwb_f32_kernel(const float* __restrict__ rel, const float* __restrict__ W,
                               const float* __restrict__ b, float* __restrict__ rwb, int R) {
    const int k = blockIdx.x;
    const int n = threadIdx.x;
    __shared__ float relk[128];
    relk[n] = rel[(size_t)k * 128 + n];
    __syncthreads();
    const float4* w4 = reinterpret_cast<const float4*>(W + (size_t)n * 128);
    const float4* r4 = reinterpret_cast<const float4*>(relk);
    float acc = 0.f;
#pragma unroll
    for (int i = 0; i < 32; ++i) {
        float4 a = r4[i], w = w4[i];
        acc += a.x * w.x + a.y * w.y + a.z * w.z + a.w * w.w;
    }
    rwb[(size_t)k * 128 + n] = acc + b[n];
}

__global__ void scatter_vec_kernel(const int* __restrict__ heads, const int* __restrict__ tails,
                                   const int* __restrict__ rels, const float* __restrict__ val,
                                   const float* __restrict__ rwb, float* __restrict__ out,
                                   long long nitems) {
    const long long i = (long long)blockIdx.x * blockDim.x + threadIdx.x;
    if (i >= nitems) return;
    const int e = (int)(i >> 5);
    const int c = (int)(i & 31) * 4;
    const float v = val[e];
    float4 rw = *reinterpret_cast<const float4*>(rwb + (size_t)rels[e] * 128 + c);
    float* pt = out + (size_t)tails[e] * 128 + c;
    float* ph = out + (size_t)heads[e] * 128 + c;
    unsafeAtomicAdd(pt + 0, v * rw.x); unsafeAtomicAdd(pt + 1, v * rw.y);
    unsafeAtomicAdd(pt + 2, v * rw.z); unsafeAtomicAdd(pt + 3, v * rw.w);
    unsafeAtomicAdd(ph + 0, v * rw.x); unsafeAtomicAdd(ph + 1, v * rw.y);
    unsafeAtomicAdd(ph + 2, v * rw.z); unsafeAtomicAdd(ph + 3, v * rw.w);
}

__global__ void relu_kernel(float* __restrict__ out, int n4) {
    const int i = blockIdx.x * blockDim.x + threadIdx.x;
    if (i >= n4) return;
    float4* p = reinterpret_cast<float4*>(out) + i;
    float4 v = *p;
    v.x = fmaxf(v.x, 0.f); v.y = fmaxf(v.y, 0.f);
    v.z = fmaxf(v.z, 0.f); v.w = fmaxf(v.w, 0.f);
    *p = v;
}

// ---------------------------------------------------------------------------
extern "C" void kernel_launch(void* const* d_in, const int* in_sizes, int n_in,
                              void* d_out, int out_size, void* d_ws, size_t ws_size,
                              hipStream_t stream) {
    // inputs: 0 local_entity [B*M] (shape only), 1 heads [E], 2 tails [E],
    //         3 rels [E], 4 val [E], 5 rel_features [R*D], 6 W [D*D], 7 b [D]
    const int* heads = (const int*)d_in[1];
    const int* tails = (const int*)d_in[2];
    const int* rels  = (const int*)d_in[3];
    const float* val  = (const float*)d_in[4];
    const float* relf = (const float*)d_in[5];
    const float* W    = (const float*)d_in[6];
    const float* b    = (const float*)d_in[7];
    float* out = (float*)d_out;

    const int NUMENT = in_sizes[0];          // 16000
    const int E      = in_sizes[1];          // 2,000,000
    const int D      = in_sizes[7];          // 128
    const int R      = in_sizes[5] / D;      // 2000

    // workspace carve-up
    const size_t rwb_bytes  = (size_t)R * D * sizeof(_Float16);        // 512 KB
    const size_t off_cnt    = (rwb_bytes + 255) & ~(size_t)255;
    const size_t cnt_bytes  = (size_t)NUMENT * 32 * sizeof(int);       // 2 MB (1 counter / 128B line)
    const size_t off_slots  = (off_cnt + cnt_bytes + 255) & ~(size_t)255;

    int CAP = 0;
    if (ws_size > off_slots) {
        size_t capmax = (ws_size - off_slots) / ((size_t)NUMENT * sizeof(uint2));
        CAP = (int)((capmax / 64) * 64);
        if (CAP > 512) CAP = 512;            // Poisson(250) degrees: 512 is >15 sigma
    }

    if (CAP >= 384) {
        _Float16* rwb = (_Float16*)d_ws;
        int* cnt      = (int*)((char*)d_ws + off_cnt);
        uint2* slots  = (uint2*)((char*)d_ws + off_slots);

        hipMemsetAsync(cnt, 0, cnt_bytes, stream);
        hipMemsetAsync(out, 0, (size_t)out_size * sizeof(float), stream);
        rwb_row_kernel<<<R, 128, 0, stream>>>(relf, W, b, rwb, R);
        scatter2_kernel<<<(E + 255) / 256, 256, 0, stream>>>(
            heads, tails, rels, val, cnt, slots, rwb, out, E, CAP);
        gather_kernel<<<(NUMENT + 3) / 4, 256, 0, stream>>>(
            slots, cnt, rwb, out, NUMENT, CAP);
    } else {
        // fallback: accumulate directly into out (slow but small-ws safe)
        float* rwb = (float*)d_ws;           // R*D fp32 (~1 MB)
        hipMemsetAsync(out, 0, (size_t)out_size * sizeof(float), stream);
        rwb_f32_kernel<<<R, 128, 0, stream>>>(relf, W, b, rwb, R);
        const long long items = (long long)E * 32;
        scatter_vec_kernel<<<(unsigned)((items + 255) / 256), 256, 0, stream>>>(
            heads, tails, rels, val, rwb, out, items);
        relu_kernel<<<(out_size / 4 + 255) / 256, 256, 0, stream>>>(out, out_size / 4);
    }
}